// Round 11
// baseline (277.522 us; speedup 1.0000x reference)
//
#include <hip/hip_runtime.h>
#include <hip/hip_cooperative_groups.h>
#include <cstdint>

namespace cg = cooperative_groups;

#define NPOINTS 524288
#define NLEV 24
#define CAP 262144
#define HASHMUL 2531011u
#define PTS_PER_BLOCK 512
#define BLOCKS_PER_LEVEL (NPOINTS / PTS_PER_BLOCK)   // 1024

#define NBUCKET 16384             // 5+5+4-bit spatial code
#define SORT_BLOCKS 64
#define SORT_PTS (NPOINTS / SORT_BLOCKS)             // 8192 points per sort block

#define WS_H_B   ((size_t)NLEV * NPOINTS * 4)        // 50,331,648 (half2 per (l,n))
#define POS4_B   ((size_t)NPOINTS * 16)              //  8,388,608
#define PART_B   ((size_t)SORT_BLOCKS * NBUCKET * 4) //  4,194,304
#define BASE_B   PART_B
#define BT_B     ((size_t)4096)

typedef float v2f  __attribute__((ext_vector_type(2)));
typedef float v4f  __attribute__((ext_vector_type(4)));
typedef _Float16 f16x2 __attribute__((ext_vector_type(2)));

// ---------------- fused cooperative sort (no global atomics) ----------------

__device__ __forceinline__ uint32_t expand_bits(uint32_t v) {
    v = (v | (v << 16)) & 0x030000FFu;
    v = (v | (v << 8))  & 0x0300F00Fu;
    v = (v | (v << 4))  & 0x030C30C3u;
    v = (v | (v << 2))  & 0x09249249u;
    return v;
}

// 14-bit code: 12-bit morton of (x&15, y&15, z) + top bits (x>>4, y>>4)
__device__ __forceinline__ uint32_t bucket_code(float x, float y, float z) {
    int xi = (int)(x * 32.0f); xi = xi < 0 ? 0 : (xi > 31 ? 31 : xi);
    int yi = (int)(y * 32.0f); yi = yi < 0 ? 0 : (yi > 31 ? 31 : yi);
    int zi = (int)(z * 16.0f); zi = zi < 0 ? 0 : (zi > 15 ? 15 : zi);
    uint32_t m = expand_bits((uint32_t)(xi & 15))
               | (expand_bits((uint32_t)(yi & 15)) << 1)
               | (expand_bits((uint32_t)zi) << 2);
    return m | ((uint32_t)(yi >> 4) << 12) | ((uint32_t)(xi >> 4) << 13);
}

// One kernel: hist -> scan -> base -> scatter, 3 grid syncs on 64 blocks.
__global__ __launch_bounds__(256) void sort_coop(
    const float* __restrict__ pos,   // [N,3]
    int* __restrict__ part,          // [SORT_BLOCKS][NBUCKET]
    int* __restrict__ base,          // [SORT_BLOCKS][NBUCKET]
    int* __restrict__ blockTot,      // [SORT_BLOCKS]
    v4f* __restrict__ pos4)          // [N] {x,y,z,orig}
{
    cg::grid_group grid = cg::this_grid();
    __shared__ int h[NBUCKET];       // 64 KB
    const int t = threadIdx.x, b = blockIdx.x;
    const int n0 = b * SORT_PTS;

    // phase A: per-block LDS histogram -> part[b][*]
    for (int i = t; i < NBUCKET; i += 256) h[i] = 0;
    __syncthreads();
    for (int i = 0; i < SORT_PTS / 256; ++i) {
        const int n = n0 + i * 256 + t;
        atomicAdd(&h[bucket_code(pos[n*3], pos[n*3+1], pos[n*3+2])], 1);
    }
    __syncthreads();
    for (int i = t; i < NBUCKET; i += 256) part[b * NBUCKET + i] = h[i];
    grid.sync();

    // phase B: bucket j = b*256 + t (one per thread); total + block scan
    const int j = b * 256 + t;
    int tot = 0;
    #pragma unroll 8
    for (int bb = 0; bb < SORT_BLOCKS; ++bb) tot += part[bb * NBUCKET + j];
    __syncthreads();
    h[t] = tot;
    __syncthreads();
    for (int d = 1; d < 256; d <<= 1) {
        int v = (t >= d) ? h[t - d] : 0;
        __syncthreads();
        h[t] += v;
        __syncthreads();
    }
    const int excl = h[t] - tot;     // exclusive prefix within block's buckets
    if (t == 255) blockTot[b] = h[255];
    grid.sync();

    // phase C: cross-block prefix, then base[bb][j]
    if (t < SORT_BLOCKS) h[256 + t] = blockTot[t];
    __syncthreads();
    int G0 = 0;
    for (int i = 0; i < b; ++i) G0 += h[256 + i];
    int run = G0 + excl;
    #pragma unroll 8
    for (int bb = 0; bb < SORT_BLOCKS; ++bb) {
        base[bb * NBUCKET + j] = run;
        run += part[bb * NBUCKET + j];
    }
    grid.sync();

    // phase D: scatter via LDS counters seeded with this block's bases
    for (int i = t; i < NBUCKET; i += 256) h[i] = base[b * NBUCKET + i];
    __syncthreads();
    for (int i = 0; i < SORT_PTS / 256; ++i) {
        const int n = n0 + i * 256 + t;
        const float x = pos[n*3], y = pos[n*3+1], z = pos[n*3+2];
        const int slot = atomicAdd(&h[bucket_code(x, y, z)], 1);
        v4f v; v.x = x; v.y = y; v.z = z; v.w = __uint_as_float((uint32_t)n);
        pos4[slot] = v;
    }
}

// ---------------- permuto core ----------------

__device__ __forceinline__ void prep_point(
    const float p0, const float p1, const float p2,
    const float sf0, const float sf1, const float sf2,
    const float sh0, const float sh1, const float sh2,
    uint32_t* __restrict__ ix, float* __restrict__ w)
{
    const float cf0 = (p0 + sh0) * sf0;
    const float cf1 = (p1 + sh1) * sf1;
    const float cf2 = (p2 + sh2) * sf2;

    const float S2 = cf2;
    const float S1 = cf2 + cf1;
    const float S0 = S1 + cf0;

    float E[4];
    E[0] = S0;
    E[1] = S1 - 1.0f*cf0;
    E[2] = S2 - 2.0f*cf1;
    E[3] = 0.0f - 3.0f*cf2;

    float rem0[4];
    float sumrem = 0.0f;
    #pragma unroll
    for (int i = 0; i < 4; ++i) {
        float v  = E[i] * 0.25f;
        float up = ceilf(v)  * 4.0f;
        float dn = floorf(v) * 4.0f;
        rem0[i] = (up - E[i] < E[i] - dn) ? up : dn;
        sumrem += rem0[i];
    }
    const int sum_val = (int)rintf(sumrem * 0.25f);

    float diff[4];
    #pragma unroll
    for (int i = 0; i < 4; ++i) diff[i] = E[i] - rem0[i];

    int rank[4];
    #pragma unroll
    for (int i = 0; i < 4; ++i) {
        int rk = 0;
        #pragma unroll
        for (int j = 0; j < 4; ++j) {
            if (j > i)      rk += (diff[j] >  diff[i]) ? 1 : 0;
            else if (j < i) rk += (diff[j] >= diff[i]) ? 1 : 0;
        }
        rk += sum_val;
        if (rk < 0)      { rk += 4; rem0[i] += 4.0f; }
        else if (rk > 3) { rk -= 4; rem0[i] -= 4.0f; }
        rank[i] = rk;
    }

    float delta[4];
    #pragma unroll
    for (int i = 0; i < 4; ++i) delta[i] = (E[i] - rem0[i]) * 0.25f;

    float b[5];
    #pragma unroll
    for (int k = 0; k < 5; ++k) {
        float acc = 0.0f;
        #pragma unroll
        for (int i = 0; i < 4; ++i) {
            int ti = 3 - rank[i];
            float m = ((ti == k) ? 1.0f : 0.0f) - ((ti == (k-1)) ? 1.0f : 0.0f);
            acc += delta[i] * m;
        }
        b[k] = acc;
    }
    b[0] += 1.0f + b[4];

    int rem0i[4];
    #pragma unroll
    for (int i = 0; i < 4; ++i) rem0i[i] = (int)rintf(rem0[i]);

    #pragma unroll
    for (int r = 0; r < 4; ++r) {
        uint32_t h = 0u;
        #pragma unroll
        for (int i = 0; i < 3; ++i) {
            int key = rem0i[i] + r - 4 * ((rank[i] > 3 - r) ? 1 : 0);
            h = (h + (uint32_t)key) * HASHMUL;
        }
        ix[r] = h & (uint32_t)(CAP - 1);
        w[r]  = b[r];
    }
}

__device__ __forceinline__ uint32_t pack_h2_scaled(float x, float y) {
    f16x2 ph;
    ph.x = (_Float16)(x * 256.0f);   // *2^8 exact; keeps values in f16 normal range
    ph.y = (_Float16)(y * 256.0f);
    return __builtin_bit_cast(uint32_t, ph);
}

// One block = (one XCD's 3 levels, 512 sorted points), 2 points per thread.
__global__ __launch_bounds__(256, 6) void permuto_kernel(
    const v4f* __restrict__ pos4,       // [N] {x,y,z,orig} sorted
    const float* __restrict__ lattice,  // [L,C,2]
    const float* __restrict__ shift,    // [L,3]
    const float* __restrict__ anneal,   // [L]
    const float* __restrict__ scale,    // [L]
    uint32_t* __restrict__ ws_u)        // [L][N] half2 (scaled by 256)
{
    __shared__ v4f s_pos[PTS_PER_BLOCK];   // 8 KB

    const int t    = threadIdx.x;
    const int bid  = blockIdx.x;
    const int xcd  = bid & 7;
    const int nb   = bid >> 3;            // 0..1023
    const int pbase = nb * PTS_PER_BLOCK;

    {
        const v4f* src = pos4 + pbase;
        s_pos[t]       = src[t];
        s_pos[t + 256] = src[t + 256];
    }
    __syncthreads();

    const v4f pA = s_pos[t];
    const v4f pB = s_pos[t + 256];

    for (int ph = 0; ph < 3; ++ph) {
        const int l = xcd + 8 * ph;

        const float sc  = scale[l];
        const float sf0 = sc / sqrtf(2.0f);
        const float sf1 = sc / sqrtf(6.0f);
        const float sf2 = sc / sqrtf(12.0f);
        const float sh0 = shift[l*3+0];
        const float sh1 = shift[l*3+1];
        const float sh2 = shift[l*3+2];
        const float an  = anneal[l];

        uint32_t ixA[4], ixB[4];
        float    wA[4],  wB[4];
        prep_point(pA.x, pA.y, pA.z, sf0, sf1, sf2, sh0, sh1, sh2, ixA, wA);
        prep_point(pB.x, pB.y, pB.z, sf0, sf1, sf2, sh0, sh1, sh2, ixB, wB);

        const v2f* __restrict__ tbl =
            reinterpret_cast<const v2f*>(lattice) + (size_t)l * CAP;

        v2f vA[4], vB[4];
        #pragma unroll
        for (int r = 0; r < 4; ++r) vA[r] = tbl[ixA[r]];
        #pragma unroll
        for (int r = 0; r < 4; ++r) vB[r] = tbl[ixB[r]];

        float oA0 = 0.f, oA1 = 0.f, oB0 = 0.f, oB1 = 0.f;
        #pragma unroll
        for (int r = 0; r < 4; ++r) {
            oA0 += wA[r] * vA[r].x;  oA1 += wA[r] * vA[r].y;
            oB0 += wB[r] * vB[r].x;  oB1 += wB[r] * vB[r].y;
        }

        const uint32_t uA = pack_h2_scaled(oA0 * an, oA1 * an);
        const uint32_t uB = pack_h2_scaled(oB0 * an, oB1 * an);

        uint32_t* pWA = ws_u + (size_t)l * NPOINTS + pbase + t;
        __builtin_nontemporal_store(uA, pWA);
        __builtin_nontemporal_store(uB, pWA + 256);
    }
}

// LDS-free transpose: 4 lanes per point; lane m holds output cols 12m..12m+11.
__global__ __launch_bounds__(256) void transpose_kernel(
    const uint32_t* __restrict__ ws_u,   // [L][N] half2 scaled
    const uint32_t* __restrict__ pos4u,  // pos4 as uints (w = orig index)
    float* __restrict__ out)             // [N][48]
{
    const int t  = threadIdx.x;
    const int m  = t & 3;
    const int p  = blockIdx.x * 64 + (t >> 2);

    const uint32_t orig = pos4u[4*p + 3];

    float r[12];
    #pragma unroll
    for (int i = 0; i < 6; ++i) {
        const int l = m * 6 + i;
        const uint32_t u = ws_u[(size_t)l * NPOINTS + p];
        const f16x2 hh = __builtin_bit_cast(f16x2, u);
        r[2*i+0] = (float)hh.x * 0.00390625f;   // /256 exact
        r[2*i+1] = (float)hh.y * 0.00390625f;
    }

    float* orow = out + (size_t)orig * 48 + m * 12;
    #pragma unroll
    for (int j = 0; j < 3; ++j) {
        v4f v; v.x = r[4*j]; v.y = r[4*j+1]; v.z = r[4*j+2]; v.w = r[4*j+3];
        *reinterpret_cast<v4f*>(orow + 4*j) = v;
    }
}

// Fallback (ws too small): unsorted, direct scattered out writes.
__global__ __launch_bounds__(256) void permuto_direct(
    const float* __restrict__ pos,
    const float* __restrict__ lattice,
    const float* __restrict__ shift,
    const float* __restrict__ anneal,
    const float* __restrict__ scale,
    float* __restrict__ out)
{
    const int tid = blockIdx.x * 256 + threadIdx.x;
    const int n = tid / NLEV;
    const int l = tid - n * NLEV;

    const float sc  = scale[l];
    const float sf0 = sc / sqrtf(2.0f);
    const float sf1 = sc / sqrtf(6.0f);
    const float sf2 = sc / sqrtf(12.0f);

    uint32_t ix[4]; float w[4];
    prep_point(pos[n*3+0], pos[n*3+1], pos[n*3+2],
               sf0, sf1, sf2, shift[l*3+0], shift[l*3+1], shift[l*3+2], ix, w);

    const v2f* tbl = reinterpret_cast<const v2f*>(lattice) + (size_t)l * CAP;
    float o0 = 0.f, o1 = 0.f;
    #pragma unroll
    for (int r = 0; r < 4; ++r) {
        v2f v = tbl[ix[r]];
        o0 += w[r] * v.x;  o1 += w[r] * v.y;
    }
    const float an = anneal[l];
    v2f res; res.x = o0 * an; res.y = o1 * an;
    *reinterpret_cast<v2f*>(out + (size_t)n * (NLEV*2) + l*2) = res;
}

extern "C" void kernel_launch(void* const* d_in, const int* in_sizes, int n_in,
                              void* d_out, int out_size, void* d_ws, size_t ws_size,
                              hipStream_t stream) {
    const float* pos     = (const float*)d_in[0];
    const float* lattice = (const float*)d_in[1];
    const float* shift   = (const float*)d_in[2];
    const float* anneal  = (const float*)d_in[3];
    const float* scale   = (const float*)d_in[4];
    float* out = (float*)d_out;

    uint8_t* w8 = (uint8_t*)d_ws;
    uint32_t* ws_u  = (uint32_t*)w8;
    v4f*      pos4  = (v4f*)(w8 + WS_H_B);
    int*      part  = (int*)(w8 + WS_H_B + POS4_B);
    int*      basep = (int*)(w8 + WS_H_B + POS4_B + PART_B);
    int*      btot  = (int*)(w8 + WS_H_B + POS4_B + PART_B + BASE_B);
    const size_t need = WS_H_B + POS4_B + PART_B + BASE_B + BT_B;

    if (ws_size >= need) {
        void* args[] = { (void*)&pos, (void*)&part, (void*)&basep,
                         (void*)&btot, (void*)&pos4 };
        hipLaunchCooperativeKernel(reinterpret_cast<void*>(sort_coop),
                                   dim3(SORT_BLOCKS), dim3(256), args, 0, stream);
        permuto_kernel<<<BLOCKS_PER_LEVEL * 8, 256, 0, stream>>>(
            pos4, lattice, shift, anneal, scale, ws_u);
        transpose_kernel<<<NPOINTS / 64, 256, 0, stream>>>(
            ws_u, (const uint32_t*)pos4, out);
    } else {
        permuto_direct<<<(NPOINTS * NLEV) / 256, 256, 0, stream>>>(
            pos, lattice, shift, anneal, scale, out);
    }
}

// Round 12
// 236.824 us; speedup vs baseline: 1.1718x; 1.1718x over previous
//
#include <hip/hip_runtime.h>
#include <cstdint>

#define NPOINTS 524288
#define NLEV 24
#define CAP 262144
#define HASHMUL 2531011u
#define PTS_PER_BLOCK 512
#define BLOCKS_PER_LEVEL (NPOINTS / PTS_PER_BLOCK)   // 1024

#define NBUCKET 16384             // 5+5+4-bit spatial code
#define SORT_BLOCKS 64
#define SORT_PTS (NPOINTS / SORT_BLOCKS)             // 8192 points per sort block

#define WS_H_B   ((size_t)NLEV * NPOINTS * 4)        // 50,331,648 (half2 per (l,n))
#define POS4_B   ((size_t)NPOINTS * 16)              //  8,388,608
#define PART_B   ((size_t)SORT_BLOCKS * NBUCKET * 4) //  4,194,304
#define BASE_B   PART_B
#define TOT_B    ((size_t)NBUCKET * 4)               //     65,536

typedef float v2f  __attribute__((ext_vector_type(2)));
typedef float v4f  __attribute__((ext_vector_type(4)));
typedef _Float16 f16x2 __attribute__((ext_vector_type(2)));

// ---------------- sorting (multi-kernel, no global atomics) ----------------

__device__ __forceinline__ uint32_t expand_bits(uint32_t v) {
    v = (v | (v << 16)) & 0x030000FFu;
    v = (v | (v << 8))  & 0x0300F00Fu;
    v = (v | (v << 4))  & 0x030C30C3u;
    v = (v | (v << 2))  & 0x09249249u;
    return v;
}

// 14-bit code: 12-bit morton of (x&15, y&15, z) + top bits (x>>4, y>>4)
__device__ __forceinline__ uint32_t bucket_code(float x, float y, float z) {
    int xi = (int)(x * 32.0f); xi = xi < 0 ? 0 : (xi > 31 ? 31 : xi);
    int yi = (int)(y * 32.0f); yi = yi < 0 ? 0 : (yi > 31 ? 31 : yi);
    int zi = (int)(z * 16.0f); zi = zi < 0 ? 0 : (zi > 15 ? 15 : zi);
    uint32_t m = expand_bits((uint32_t)(xi & 15))
               | (expand_bits((uint32_t)(yi & 15)) << 1)
               | (expand_bits((uint32_t)zi) << 2);
    return m | ((uint32_t)(yi >> 4) << 12) | ((uint32_t)(xi >> 4) << 13);
}

// per-block LDS histogram -> part[b][j]
__global__ __launch_bounds__(256) void hist_kernel(
    const float* __restrict__ pos, int* __restrict__ part) {
    __shared__ int h[NBUCKET];     // 64 KB
    const int t = threadIdx.x, b = blockIdx.x;
    for (int i = t; i < NBUCKET; i += 256) h[i] = 0;
    __syncthreads();
    const int n0 = b * SORT_PTS;
    for (int i = 0; i < SORT_PTS / 256; ++i) {
        const int n = n0 + i * 256 + t;
        atomicAdd(&h[bucket_code(pos[n*3], pos[n*3+1], pos[n*3+2])], 1);
    }
    __syncthreads();
    for (int i = t; i < NBUCKET; i += 256) part[b * NBUCKET + i] = h[i];
}

// tot[j] = sum_b part[b][j]
__global__ __launch_bounds__(256) void scanA_kernel(
    const int* __restrict__ part, int* __restrict__ tot) {
    const int j = blockIdx.x * 256 + threadIdx.x;
    int s = 0;
    #pragma unroll 8
    for (int b = 0; b < SORT_BLOCKS; ++b) s += part[b * NBUCKET + j];
    tot[j] = s;
}

// single-block exclusive scan of tot[NBUCKET] -> G (re-reads tot, L2-hit)
__global__ __launch_bounds__(256) void scanB_kernel(
    const int* __restrict__ tot, int* __restrict__ G) {
    __shared__ int sums[256];
    const int t = threadIdx.x;
    const int CH = NBUCKET / 256;   // 64
    const int base = t * CH;
    int s = 0;
    for (int k = 0; k < CH; ++k) s += tot[base + k];
    sums[t] = s;
    __syncthreads();
    for (int d = 1; d < 256; d <<= 1) {
        int v = (t >= d) ? sums[t - d] : 0;
        __syncthreads();
        sums[t] += v;
        __syncthreads();
    }
    int run = sums[t] - s;
    for (int k = 0; k < CH; ++k) { G[base + k] = run; run += tot[base + k]; }
}

// base[b][j] = G[j] + sum_{b'<b} part[b'][j]
__global__ __launch_bounds__(256) void scanC_kernel(
    const int* __restrict__ part, const int* __restrict__ G,
    int* __restrict__ base) {
    const int j = blockIdx.x * 256 + threadIdx.x;
    int run = G[j];
    #pragma unroll 8
    for (int b = 0; b < SORT_BLOCKS; ++b) {
        base[b * NBUCKET + j] = run;
        run += part[b * NBUCKET + j];
    }
}

// scatter via LDS counters seeded with per-block bases
__global__ __launch_bounds__(256) void scatter_kernel(
    const float* __restrict__ pos, const int* __restrict__ base,
    v4f* __restrict__ pos4) {
    __shared__ int cnt[NBUCKET];   // 64 KB
    const int t = threadIdx.x, b = blockIdx.x;
    for (int i = t; i < NBUCKET; i += 256) cnt[i] = base[b * NBUCKET + i];
    __syncthreads();
    const int n0 = b * SORT_PTS;
    for (int i = 0; i < SORT_PTS / 256; ++i) {
        const int n = n0 + i * 256 + t;
        const float x = pos[n*3], y = pos[n*3+1], z = pos[n*3+2];
        const int slot = atomicAdd(&cnt[bucket_code(x, y, z)], 1);
        v4f v; v.x = x; v.y = y; v.z = z; v.w = __uint_as_float((uint32_t)n);
        pos4[slot] = v;
    }
}

// ---------------- permuto core ----------------

__device__ __forceinline__ void prep_point(
    const float p0, const float p1, const float p2,
    const float sf0, const float sf1, const float sf2,
    const float sh0, const float sh1, const float sh2,
    uint32_t* __restrict__ ix, float* __restrict__ w)
{
    const float cf0 = (p0 + sh0) * sf0;
    const float cf1 = (p1 + sh1) * sf1;
    const float cf2 = (p2 + sh2) * sf2;

    const float S2 = cf2;
    const float S1 = cf2 + cf1;
    const float S0 = S1 + cf0;

    float E[4];
    E[0] = S0;
    E[1] = S1 - 1.0f*cf0;
    E[2] = S2 - 2.0f*cf1;
    E[3] = 0.0f - 3.0f*cf2;

    float rem0[4];
    float sumrem = 0.0f;
    #pragma unroll
    for (int i = 0; i < 4; ++i) {
        float v  = E[i] * 0.25f;
        float up = ceilf(v)  * 4.0f;
        float dn = floorf(v) * 4.0f;
        rem0[i] = (up - E[i] < E[i] - dn) ? up : dn;
        sumrem += rem0[i];
    }
    const int sum_val = (int)rintf(sumrem * 0.25f);

    float diff[4];
    #pragma unroll
    for (int i = 0; i < 4; ++i) diff[i] = E[i] - rem0[i];

    int rank[4];
    #pragma unroll
    for (int i = 0; i < 4; ++i) {
        int rk = 0;
        #pragma unroll
        for (int j = 0; j < 4; ++j) {
            if (j > i)      rk += (diff[j] >  diff[i]) ? 1 : 0;
            else if (j < i) rk += (diff[j] >= diff[i]) ? 1 : 0;
        }
        rk += sum_val;
        if (rk < 0)      { rk += 4; rem0[i] += 4.0f; }
        else if (rk > 3) { rk -= 4; rem0[i] -= 4.0f; }
        rank[i] = rk;
    }

    float delta[4];
    #pragma unroll
    for (int i = 0; i < 4; ++i) delta[i] = (E[i] - rem0[i]) * 0.25f;

    float b[5];
    #pragma unroll
    for (int k = 0; k < 5; ++k) {
        float acc = 0.0f;
        #pragma unroll
        for (int i = 0; i < 4; ++i) {
            int ti = 3 - rank[i];
            float m = ((ti == k) ? 1.0f : 0.0f) - ((ti == (k-1)) ? 1.0f : 0.0f);
            acc += delta[i] * m;
        }
        b[k] = acc;
    }
    b[0] += 1.0f + b[4];

    int rem0i[4];
    #pragma unroll
    for (int i = 0; i < 4; ++i) rem0i[i] = (int)rintf(rem0[i]);

    #pragma unroll
    for (int r = 0; r < 4; ++r) {
        uint32_t h = 0u;
        #pragma unroll
        for (int i = 0; i < 3; ++i) {
            int key = rem0i[i] + r - 4 * ((rank[i] > 3 - r) ? 1 : 0);
            h = (h + (uint32_t)key) * HASHMUL;
        }
        ix[r] = h & (uint32_t)(CAP - 1);
        w[r]  = b[r];
    }
}

__device__ __forceinline__ uint32_t pack_h2_scaled(float x, float y) {
    f16x2 ph;
    ph.x = (_Float16)(x * 256.0f);   // *2^8 exact; keeps values in f16 normal range
    ph.y = (_Float16)(y * 256.0f);
    return __builtin_bit_cast(uint32_t, ph);
}

// One block = (one XCD's 3 levels, 512 sorted points), 2 points per thread.
__global__ __launch_bounds__(256, 6) void permuto_kernel(
    const v4f* __restrict__ pos4,       // [N] {x,y,z,orig} sorted
    const float* __restrict__ lattice,  // [L,C,2]
    const float* __restrict__ shift,    // [L,3]
    const float* __restrict__ anneal,   // [L]
    const float* __restrict__ scale,    // [L]
    uint32_t* __restrict__ ws_u)        // [L][N] half2 (scaled by 256)
{
    __shared__ v4f s_pos[PTS_PER_BLOCK];   // 8 KB

    const int t    = threadIdx.x;
    const int bid  = blockIdx.x;
    const int xcd  = bid & 7;
    const int nb   = bid >> 3;            // 0..1023
    const int pbase = nb * PTS_PER_BLOCK;

    {
        const v4f* src = pos4 + pbase;
        s_pos[t]       = src[t];
        s_pos[t + 256] = src[t + 256];
    }
    __syncthreads();

    const v4f pA = s_pos[t];
    const v4f pB = s_pos[t + 256];

    for (int ph = 0; ph < 3; ++ph) {
        const int l = xcd + 8 * ph;

        const float sc  = scale[l];
        const float sf0 = sc / sqrtf(2.0f);
        const float sf1 = sc / sqrtf(6.0f);
        const float sf2 = sc / sqrtf(12.0f);
        const float sh0 = shift[l*3+0];
        const float sh1 = shift[l*3+1];
        const float sh2 = shift[l*3+2];
        const float an  = anneal[l];

        uint32_t ixA[4], ixB[4];
        float    wA[4],  wB[4];
        prep_point(pA.x, pA.y, pA.z, sf0, sf1, sf2, sh0, sh1, sh2, ixA, wA);
        prep_point(pB.x, pB.y, pB.z, sf0, sf1, sf2, sh0, sh1, sh2, ixB, wB);

        const v2f* __restrict__ tbl =
            reinterpret_cast<const v2f*>(lattice) + (size_t)l * CAP;

        v2f vA[4], vB[4];
        #pragma unroll
        for (int r = 0; r < 4; ++r) vA[r] = tbl[ixA[r]];
        #pragma unroll
        for (int r = 0; r < 4; ++r) vB[r] = tbl[ixB[r]];

        float oA0 = 0.f, oA1 = 0.f, oB0 = 0.f, oB1 = 0.f;
        #pragma unroll
        for (int r = 0; r < 4; ++r) {
            oA0 += wA[r] * vA[r].x;  oA1 += wA[r] * vA[r].y;
            oB0 += wB[r] * vB[r].x;  oB1 += wB[r] * vB[r].y;
        }

        const uint32_t uA = pack_h2_scaled(oA0 * an, oA1 * an);
        const uint32_t uB = pack_h2_scaled(oB0 * an, oB1 * an);

        uint32_t* pWA = ws_u + (size_t)l * NPOINTS + pbase + t;
        __builtin_nontemporal_store(uA, pWA);
        __builtin_nontemporal_store(uB, pWA + 256);
    }
}

// LDS-free transpose: 4 lanes per point; lane m holds output cols 12m..12m+11.
__global__ __launch_bounds__(256) void transpose_kernel(
    const uint32_t* __restrict__ ws_u,   // [L][N] half2 scaled
    const uint32_t* __restrict__ pos4u,  // pos4 as uints (w = orig index)
    float* __restrict__ out)             // [N][48]
{
    const int t  = threadIdx.x;
    const int m  = t & 3;
    const int p  = blockIdx.x * 64 + (t >> 2);

    const uint32_t orig = pos4u[4*p + 3];

    float r[12];
    #pragma unroll
    for (int i = 0; i < 6; ++i) {
        const int l = m * 6 + i;
        const uint32_t u = ws_u[(size_t)l * NPOINTS + p];
        const f16x2 hh = __builtin_bit_cast(f16x2, u);
        r[2*i+0] = (float)hh.x * 0.00390625f;   // /256 exact
        r[2*i+1] = (float)hh.y * 0.00390625f;
    }

    float* orow = out + (size_t)orig * 48 + m * 12;
    #pragma unroll
    for (int j = 0; j < 3; ++j) {
        v4f v; v.x = r[4*j]; v.y = r[4*j+1]; v.z = r[4*j+2]; v.w = r[4*j+3];
        *reinterpret_cast<v4f*>(orow + 4*j) = v;
    }
}

// Fallback (ws too small): unsorted, direct scattered out writes.
__global__ __launch_bounds__(256) void permuto_direct(
    const float* __restrict__ pos,
    const float* __restrict__ lattice,
    const float* __restrict__ shift,
    const float* __restrict__ anneal,
    const float* __restrict__ scale,
    float* __restrict__ out)
{
    const int tid = blockIdx.x * 256 + threadIdx.x;
    const int n = tid / NLEV;
    const int l = tid - n * NLEV;

    const float sc  = scale[l];
    const float sf0 = sc / sqrtf(2.0f);
    const float sf1 = sc / sqrtf(6.0f);
    const float sf2 = sc / sqrtf(12.0f);

    uint32_t ix[4]; float w[4];
    prep_point(pos[n*3+0], pos[n*3+1], pos[n*3+2],
               sf0, sf1, sf2, shift[l*3+0], shift[l*3+1], shift[l*3+2], ix, w);

    const v2f* tbl = reinterpret_cast<const v2f*>(lattice) + (size_t)l * CAP;
    float o0 = 0.f, o1 = 0.f;
    #pragma unroll
    for (int r = 0; r < 4; ++r) {
        v2f v = tbl[ix[r]];
        o0 += w[r] * v.x;  o1 += w[r] * v.y;
    }
    const float an = anneal[l];
    v2f res; res.x = o0 * an; res.y = o1 * an;
    *reinterpret_cast<v2f*>(out + (size_t)n * (NLEV*2) + l*2) = res;
}

extern "C" void kernel_launch(void* const* d_in, const int* in_sizes, int n_in,
                              void* d_out, int out_size, void* d_ws, size_t ws_size,
                              hipStream_t stream) {
    const float* pos     = (const float*)d_in[0];
    const float* lattice = (const float*)d_in[1];
    const float* shift   = (const float*)d_in[2];
    const float* anneal  = (const float*)d_in[3];
    const float* scale   = (const float*)d_in[4];
    float* out = (float*)d_out;

    uint8_t* w8 = (uint8_t*)d_ws;
    uint32_t* ws_u  = (uint32_t*)w8;
    v4f*      pos4  = (v4f*)(w8 + WS_H_B);
    int*      part  = (int*)(w8 + WS_H_B + POS4_B);
    int*      basep = (int*)(w8 + WS_H_B + POS4_B + PART_B);
    int*      tot   = (int*)(w8 + WS_H_B + POS4_B + PART_B + BASE_B);
    int*      G     = (int*)(w8 + WS_H_B + POS4_B + PART_B + BASE_B + TOT_B);
    const size_t need = WS_H_B + POS4_B + PART_B + BASE_B + 2 * TOT_B;

    if (ws_size >= need) {
        hist_kernel   <<<SORT_BLOCKS, 256, 0, stream>>>(pos, part);
        scanA_kernel  <<<NBUCKET / 256, 256, 0, stream>>>(part, tot);
        scanB_kernel  <<<1, 256, 0, stream>>>(tot, G);
        scanC_kernel  <<<NBUCKET / 256, 256, 0, stream>>>(part, G, basep);
        scatter_kernel<<<SORT_BLOCKS, 256, 0, stream>>>(pos, basep, pos4);
        permuto_kernel<<<BLOCKS_PER_LEVEL * 8, 256, 0, stream>>>(
            pos4, lattice, shift, anneal, scale, ws_u);
        transpose_kernel<<<NPOINTS / 64, 256, 0, stream>>>(
            ws_u, (const uint32_t*)pos4, out);
    } else {
        permuto_direct<<<(NPOINTS * NLEV) / 256, 256, 0, stream>>>(
            pos, lattice, shift, anneal, scale, out);
    }
}